// Round 14
// baseline (216.977 us; speedup 1.0000x reference)
//
#include <hip/hip_runtime.h>

// MMD, 7-gamma Gaussian kernel, x,y: [8192,128] fp32.
// Round 11 design (resubmit x4; rounds 11/12/13 benches were GPUAcquisitionTimeout):
//  1) counted-vmcnt triple-buffer pipeline (T3/T4): STAGE(ks+1) ->
//     s_waitcnt vmcnt(4) -> raw s_barrier -> compute. Next chunk's loads stay
//     in flight across the barrier (round-10 limiter: 9 full vmcnt(0) drains
//     per block, only ~2.5 blocks/CU to hide them).
//  2) wave-uniform isdiag hoisted out of the epilogue pair loop.
//  3) norms fused into convert_kernel (identical reduction order -> bit-exact);
//     diag folded into mmd grid tail (+64 blocks, byte-identical math).
// Race audit: barriers each iteration keep waves <=1 interval apart; writer
// at iter ks touches buf[(ks+1)%3], readers touch ks%3 / (ks-1)%3 — disjoint.
// Numerics bit-identical to rounds 5..10 (same ks-order accumulation).

#define N_PTS 8192
#define D 128
#define TILES 64
#define TRI 2080
#define NBLK (2 * TRI + TILES * TILES)
#define NDIAG 64

typedef __attribute__((ext_vector_type(8))) short bf16x8;
typedef __attribute__((ext_vector_type(8))) unsigned short u16x8;
typedef __attribute__((ext_vector_type(4))) float f32x4;

__device__ __forceinline__ unsigned short f2bf(float a) {  // RNE
  unsigned u = __float_as_uint(a);
  return (unsigned short)((u + 0x7FFFu + ((u >> 16) & 1u)) >> 16);
}
__device__ __forceinline__ float bf2f(unsigned short b) {
  return __uint_as_float(((unsigned)b) << 16);
}

// x,y -> fragment-ordered bf16 hi|lo arrays + row norms (fused).
// 1 wave per 16-row group. Norm reduction replicates round-10 norms_kernel
// order exactly: lane q of 4 sums elements 4q+16i (i=0..7) sequentially,
// then shfl_xor 1,2 within the 4-lane group -> bit-exact norms.
__global__ __launch_bounds__(256) void convert_kernel(const float* __restrict__ x,
                                                      const float* __restrict__ y,
                                                      unsigned short* __restrict__ xf,
                                                      unsigned short* __restrict__ yf,
                                                      float* __restrict__ nx,
                                                      float* __restrict__ ny) {
  __shared__ float lds[4][16][132];
  int tid = threadIdx.x;
  int lane = tid & 63, wv = tid >> 6;
  int grp = (int)blockIdx.x * 4 + wv;        // 0..1023
  int arr = grp >> 9;
  int rowgrp = grp & 511;
  const float* src = (arr ? y : x) + (size_t)rowgrp * 16 * D;
  unsigned short* dst = (arr ? yf : xf) + (size_t)rowgrp * 4096;
  float* nrm = (arr ? ny : nx) + rowgrp * 16;

  #pragma unroll
  for (int it = 0; it < 8; it++) {
    int slot = it * 64 + lane;
    int row = slot >> 5, f4 = slot & 31;
    float4 v = *(const float4*)(src + row * D + f4 * 4);
    *(float4*)&lds[wv][row][f4 * 4] = v;
  }
  __syncthreads();

  // norms: 4 lanes per row, interleaved float4s (order == old norms_kernel)
  {
    int row = lane >> 2, q = lane & 3;
    float s = 0.f;
    #pragma unroll
    for (int i = 0; i < 8; i++) {
      float4 v = *(const float4*)&lds[wv][row][q * 4 + i * 16];
      s += v.x * v.x + v.y * v.y + v.z * v.z + v.w * v.w;
    }
    s += __shfl_xor(s, 1);
    s += __shfl_xor(s, 2);
    if (q == 0) nrm[row] = s;
  }

  // fragments
  int row = lane & 15, koct = lane >> 4;
  #pragma unroll
  for (int ks = 0; ks < 8; ks++) {
    int kp = ks * 32 + koct * 8;
    int kf = kp & 127;
    bool ishi = kp < 128;
    float v[8];
    *(float4*)&v[0] = *(const float4*)&lds[wv][row][kf];
    *(float4*)&v[4] = *(const float4*)&lds[wv][row][kf + 4];
    u16x8 o;
    #pragma unroll
    for (int j = 0; j < 8; j++) {
      unsigned short h = f2bf(v[j]);
      o[j] = ishi ? h : f2bf(v[j] - bf2f(h));
    }
    *(u16x8*)(dst + ks * 512 + lane * 8) = o;
  }
}

__global__ __launch_bounds__(256) void mmd_tile128_kernel(
    const unsigned short* __restrict__ xf, const unsigned short* __restrict__ yf,
    const float* __restrict__ x, const float* __restrict__ y,
    const float* __restrict__ nx, const float* __restrict__ ny,
    double* __restrict__ acc_out) {
  __shared__ unsigned short As[3][4096];   // [buf][rg(8)*512], 8 KB each
  __shared__ unsigned short Bs[3][4096];
  __shared__ double red[4];

  int bid = blockIdx.x;
  int tid = threadIdx.x;

  // ---- diag tail blocks: exact fp32 diagonal (byte-identical to old diag) ----
  if (bid >= NBLK) {
    double* redd = (double*)As;            // reuse LDS
    int idx = (bid - NBLK) * 256 + tid;    // 0..16383
    int arr = idx >> 13;
    int row = idx & 8191;
    const float* src = (arr ? y : x) + (size_t)row * D;
    float n = (arr ? ny : nx)[row];
    float acc = 0.f;
    #pragma unroll 4
    for (int k4 = 0; k4 < 32; k4++) {
      float4 v = *(const float4*)(src + k4 * 4);
      acc = fmaf(v.x, v.x, acc);
      acc = fmaf(v.y, v.y, acc);
      acc = fmaf(v.z, v.z, acc);
      acc = fmaf(v.w, v.w, acc);
    }
    float d = fmaf(-2.f, acc, n + n);
    d = fmaxf(d, 1e-30f);
    float s = 0.f;
    s += __expf(d * -0.001f);
    s += __expf(d * -0.01f);
    s += __expf(d * -0.1f);
    s += __expf(d * -1.0f);
    s += __expf(d * -10.0f);
    s += __expf(d * -100.0f);
    s += __expf(d * -1000.0f);
    redd[tid] = (double)s;
    __syncthreads();
    #pragma unroll
    for (int st = 128; st > 0; st >>= 1) {
      if (tid < st) redd[tid] += redd[tid + st];
      __syncthreads();
    }
    if (tid == 0) atomicAdd(acc_out, redd[0]);
    return;
  }

  // ---- pair tiles ----
  const unsigned short *Af, *Bf;
  const float *nA, *nB;
  float w;
  int ib, jb;
  bool isdiag = false;
  if (bid < 2 * TRI) {
    int t = (bid < TRI) ? bid : bid - TRI;
    int r = 0;
    while (t >= TILES - r) { t -= TILES - r; r++; }   // upper-tri decode
    ib = r; jb = r + t;
    if (bid < TRI) { Af = xf; Bf = xf; nA = nx; nB = nx; }
    else           { Af = yf; Bf = yf; nA = ny; nB = ny; }
    isdiag = (ib == jb);
    w = isdiag ? 1.0f : 2.0f;
  } else {
    int t = bid - 2 * TRI;
    ib = t >> 6; jb = t & 63;
    Af = xf; Bf = yf; nA = nx; nB = ny;
    w = -2.0f;
  }

  int lane = tid & 63, wv = tid >> 6;
  int wm = wv >> 1, wn = wv & 1;          // 2x2 waves; per-wave 64x64 out
  int r16 = lane & 15, g4 = lane >> 4;

  const unsigned short* Afrag = Af + (size_t)(ib * 8) * 4096;
  const unsigned short* Bfrag = Bf + (size_t)(jb * 8) * 4096;

  // stage one ks-slice: 8 A + 8 B slots of 1024 B; 4 gload_lds per wave.
  #define STAGE(ks, buf)                                                        \
    {                                                                           \
      _Pragma("unroll")                                                         \
      for (int i = 0; i < 4; i++) {                                             \
        int s = wv * 4 + i;                                                     \
        const unsigned short* g = (s < 8)                                       \
            ? (Afrag + (size_t)s * 4096 + (ks) * 512 + lane * 8)                \
            : (Bfrag + (size_t)(s - 8) * 4096 + (ks) * 512 + lane * 8);         \
        unsigned short* l = (s < 8) ? &As[buf][s * 512] : &Bs[buf][(s - 8) * 512]; \
        __builtin_amdgcn_global_load_lds(                                       \
            (const __attribute__((address_space(1))) void*)g,                   \
            (__attribute__((address_space(3))) void*)l, 16, 0, 0);              \
      }                                                                         \
    }

  f32x4 acc[4][4];
  #pragma unroll
  for (int m = 0; m < 4; m++)
    #pragma unroll
    for (int n = 0; n < 4; n++) acc[m][n] = (f32x4){0.f, 0.f, 0.f, 0.f};

  STAGE(0, 0);

  // counted-vmcnt pipeline: chunk ks+1 loads ride across barrier(ks).
  #pragma unroll
  for (int ks = 0; ks < 8; ks++) {
    int cur = ks % 3;
    if (ks < 7) {
      STAGE(ks + 1, (ks + 1) % 3);
      asm volatile("s_waitcnt vmcnt(4)" ::: "memory");   // my chunk-ks loads done
    } else {
      asm volatile("s_waitcnt vmcnt(0)" ::: "memory");
    }
    __builtin_amdgcn_s_barrier();                        // raw: no vmcnt drain
    __builtin_amdgcn_sched_barrier(0);
    bf16x8 a[4], b[4];
    #pragma unroll
    for (int m = 0; m < 4; m++)
      a[m] = *(const bf16x8*)&As[cur][(wm * 4 + m) * 512 + lane * 8];
    #pragma unroll
    for (int n = 0; n < 4; n++)
      b[n] = *(const bf16x8*)&Bs[cur][(wn * 4 + n) * 512 + lane * 8];
    #pragma unroll
    for (int m = 0; m < 4; m++)
      #pragma unroll
      for (int n = 0; n < 4; n++)
        acc[m][n] = __builtin_amdgcn_mfma_f32_16x16x32_bf16(a[m], b[n], acc[m][n], 0, 0, 0);
  }

  // epilogue: d = n_i + n_j - 2*dot; C/D: col=lane&15, row=(lane>>4)*4+reg
  const float* nArow = nA + ib * 128;
  const float* nBrow = nB + jb * 128;
  float nb4[4];
  #pragma unroll
  for (int n = 0; n < 4; n++) nb4[n] = nBrow[wn * 64 + n * 16 + r16];

  float lsum = 0.f;
  #define EPILOGUE(DIAGCHK)                                                     \
    _Pragma("unroll")                                                           \
    for (int m = 0; m < 4; m++) {                                               \
      float na4[4];                                                             \
      _Pragma("unroll")                                                         \
      for (int r = 0; r < 4; r++) na4[r] = nArow[wm * 64 + m * 16 + g4 * 4 + r];\
      float dv[4][4];                                                           \
      float dmin = 3.0e38f;                                                     \
      _Pragma("unroll")                                                         \
      for (int n = 0; n < 4; n++) {                                             \
        _Pragma("unroll")                                                       \
        for (int r = 0; r < 4; r++) {                                           \
          float dd = fmaf(-2.f, acc[m][n][r], na4[r] + nb4[n]);                 \
          dd = fmaxf(dd, 1e-30f);                                               \
          if (DIAGCHK) {                                                        \
            int rl = wm * 64 + m * 16 + g4 * 4 + r;                             \
            int cl = wn * 64 + n * 16 + r16;                                    \
            if (rl == cl) dd = 1e30f;  /* diag handled by tail blocks */        \
          }                                                                     \
          dv[n][r] = dd;                                                        \
          dmin = fminf(dmin, dd);                                               \
        }                                                                       \
      }                                                                         \
      if (__all(dmin > 110.f)) {                                                \
        /* exp(-g*d) == 0.0f exactly for g>=1 when d>110 (ref too) */           \
        _Pragma("unroll")                                                       \
        for (int n = 0; n < 4; n++)                                             \
          _Pragma("unroll")                                                     \
          for (int r = 0; r < 4; r++) {                                         \
            float dd = dv[n][r];                                                \
            lsum += __expf(dd * -0.001f);                                       \
            lsum += __expf(dd * -0.01f);                                        \
            lsum += __expf(dd * -0.1f);                                         \
          }                                                                     \
      } else {                                                                  \
        _Pragma("unroll")                                                       \
        for (int n = 0; n < 4; n++)                                             \
          _Pragma("unroll")                                                     \
          for (int r = 0; r < 4; r++) {                                         \
            float dd = dv[n][r];                                                \
            lsum += __expf(dd * -0.001f);                                       \
            lsum += __expf(dd * -0.01f);                                        \
            lsum += __expf(dd * -0.1f);                                         \
            lsum += __expf(dd * -1.0f);                                         \
            lsum += __expf(dd * -10.0f);                                        \
            lsum += __expf(dd * -100.0f);                                       \
            lsum += __expf(dd * -1000.0f);                                      \
          }                                                                     \
      }                                                                         \
    }

  if (isdiag) { EPILOGUE(true) } else { EPILOGUE(false) }
  #undef EPILOGUE

  double v = (double)lsum * (double)w;
  v += __shfl_xor(v, 32);
  v += __shfl_xor(v, 16);
  v += __shfl_xor(v, 8);
  v += __shfl_xor(v, 4);
  v += __shfl_xor(v, 2);
  v += __shfl_xor(v, 1);
  if (lane == 0) red[wv] = v;
  __syncthreads();
  if (tid == 0) {
    double s = red[0] + red[1] + red[2] + red[3];
    atomicAdd(acc_out, s);
  }
  #undef STAGE
}

// Fallback (round-2 kernel, no frag arrays) if ws is too small.
__global__ __launch_bounds__(256) void mmd_fallback_kernel(const float* __restrict__ X,
                                                           const float* __restrict__ Y,
                                                           const float* __restrict__ nx,
                                                           const float* __restrict__ ny,
                                                           double* __restrict__ acc_out) {
  __shared__ unsigned short As[128 * 64];
  __shared__ unsigned short Bs[128 * 64];
  __shared__ double red[256];
  int bid = blockIdx.x;
  const float *A, *B, *nA, *nB;
  float w;
  int ib, jb;
  bool isdiag = false;
  if (bid < 2 * TRI) {
    int t = (bid < TRI) ? bid : bid - TRI;
    int r = 0;
    while (t >= TILES - r) { t -= TILES - r; r++; }
    ib = r; jb = r + t;
    if (bid < TRI) { A = X; B = X; nA = nx; nB = nx; }
    else           { A = Y; B = Y; nA = ny; nB = ny; }
    isdiag = (ib == jb);
    w = isdiag ? 1.0f : 2.0f;
  } else {
    int t = bid - 2 * TRI;
    ib = t >> 6; jb = t & 63;
    A = X; B = Y; nA = nx; nB = ny;
    w = -2.0f;
  }
  int tid = threadIdx.x;
  int lane = tid & 63;
  int wv = tid >> 6, wm = wv >> 1, wn = wv & 1;
  int r16 = lane & 15, g4 = lane >> 4;
  const float* Ab = A + (size_t)ib * 128 * D;
  const float* Bb = B + (size_t)jb * 128 * D;
  f32x4 acc[4][4];
  #pragma unroll
  for (int m = 0; m < 4; m++)
    #pragma unroll
    for (int n = 0; n < 4; n++) acc[m][n] = (f32x4){0.f, 0.f, 0.f, 0.f};
  #pragma unroll 1
  for (int kc = 0; kc < 4; kc++) {
    int k0f = (kc & 1) * 64;
    bool ishi = (kc < 2);
    __syncthreads();
    #pragma unroll
    for (int s = 0; s < 4; s++) {
      int slot = tid + s * 256;
      int row = slot >> 3;
      int k2 = (slot & 7) * 8;
      const float* pa = Ab + row * D + k0f + k2;
      const float* pb = Bb + row * D + k0f + k2;
      float4 a0 = *(const float4*)pa;
      float4 a1 = *(const float4*)(pa + 4);
      float4 b0 = *(const float4*)pb;
      float4 b1 = *(const float4*)(pb + 4);
      float av[8] = {a0.x, a0.y, a0.z, a0.w, a1.x, a1.y, a1.z, a1.w};
      float bv[8] = {b0.x, b0.y, b0.z, b0.w, b1.x, b1.y, b1.z, b1.w};
      u16x8 ua, ub;
      #pragma unroll
      for (int j = 0; j < 8; j++) {
        unsigned short ha = f2bf(av[j]);
        unsigned short hb = f2bf(bv[j]);
        if (ishi) { ua[j] = (short)ha; ub[j] = (short)hb; }
        else {
          ua[j] = f2bf(av[j] - bf2f(ha));
          ub[j] = f2bf(bv[j] - bf2f(hb));
        }
      }
      int boff = row * 128 + ((k2 * 2) ^ ((row & 7) << 4));
      *(u16x8*)((char*)As + boff) = ua;
      *(u16x8*)((char*)Bs + boff) = ub;
    }
    __syncthreads();
    #pragma unroll
    for (int ks = 0; ks < 2; ks++) {
      bf16x8 af[4], bfr[4];
      int kb = ks * 64 + g4 * 16;
      #pragma unroll
      for (int m = 0; m < 4; m++) {
        int row = wm * 64 + m * 16 + r16;
        af[m] = *(const bf16x8*)((const char*)As + row * 128 + (kb ^ ((row & 7) << 4)));
      }
      #pragma unroll
      for (int n = 0; n < 4; n++) {
        int row = wn * 64 + n * 16 + r16;
        bfr[n] = *(const bf16x8*)((const char*)Bs + row * 128 + (kb ^ ((row & 7) << 4)));
      }
      #pragma unroll
      for (int m = 0; m < 4; m++)
        #pragma unroll
        for (int n = 0; n < 4; n++)
          acc[m][n] = __builtin_amdgcn_mfma_f32_16x16x32_bf16(af[m], bfr[n], acc[m][n], 0, 0, 0);
    }
  }
  const float* nArow = nA + ib * 128;
  const float* nBrow = nB + jb * 128;
  float nb4[4];
  #pragma unroll
  for (int n = 0; n < 4; n++) nb4[n] = nBrow[wn * 64 + n * 16 + r16];
  float lsum = 0.f;
  #pragma unroll
  for (int m = 0; m < 4; m++) {
    float na4[4];
    #pragma unroll
    for (int r = 0; r < 4; r++) na4[r] = nArow[wm * 64 + m * 16 + g4 * 4 + r];
    float dv[4][4];
    float dmin = 3.0e38f;
    #pragma unroll
    for (int n = 0; n < 4; n++) {
      #pragma unroll
      for (int r = 0; r < 4; r++) {
        float dd = fmaf(-2.f, acc[m][n][r], na4[r] + nb4[n]);
        dd = fmaxf(dd, 1e-30f);
        int rl = wm * 64 + m * 16 + g4 * 4 + r;
        int cl = wn * 64 + n * 16 + r16;
        if (isdiag && rl == cl) dd = 1e30f;
        dv[n][r] = dd;
        dmin = fminf(dmin, dd);
      }
    }
    if (__all(dmin > 110.f)) {
      #pragma unroll
      for (int n = 0; n < 4; n++)
        #pragma unroll
        for (int r = 0; r < 4; r++) {
          float dd = dv[n][r];
          lsum += __expf(dd * -0.001f);
          lsum += __expf(dd * -0.01f);
          lsum += __expf(dd * -0.1f);
        }
    } else {
      #pragma unroll
      for (int n = 0; n < 4; n++)
        #pragma unroll
        for (int r = 0; r < 4; r++) {
          float dd = dv[n][r];
          lsum += __expf(dd * -0.001f);
          lsum += __expf(dd * -0.01f);
          lsum += __expf(dd * -0.1f);
          lsum += __expf(dd * -1.0f);
          lsum += __expf(dd * -10.0f);
          lsum += __expf(dd * -100.0f);
          lsum += __expf(dd * -1000.0f);
        }
    }
  }
  red[tid] = (double)lsum * (double)w;
  __syncthreads();
  #pragma unroll
  for (int s = 128; s > 0; s >>= 1) {
    if (tid < s) red[tid] += red[tid + s];
    __syncthreads();
  }
  if (tid == 0) atomicAdd(acc_out, red[0]);
}

__global__ __launch_bounds__(256) void diag_kernel(const float* __restrict__ x,
                                                   const float* __restrict__ y,
                                                   const float* __restrict__ nx,
                                                   const float* __restrict__ ny,
                                                   double* __restrict__ acc_out) {
  __shared__ double red[256];
  int tid = threadIdx.x;
  int idx = (int)blockIdx.x * 256 + tid;
  int arr = idx >> 13;
  int row = idx & 8191;
  const float* src = (arr ? y : x) + (size_t)row * D;
  float n = (arr ? ny : nx)[row];
  float acc = 0.f;
  #pragma unroll 4
  for (int k4 = 0; k4 < 32; k4++) {
    float4 v = *(const float4*)(src + k4 * 4);
    acc = fmaf(v.x, v.x, acc);
    acc = fmaf(v.y, v.y, acc);
    acc = fmaf(v.z, v.z, acc);
    acc = fmaf(v.w, v.w, acc);
  }
  float d = fmaf(-2.f, acc, n + n);
  d = fmaxf(d, 1e-30f);
  float s = 0.f;
  s += __expf(d * -0.001f);
  s += __expf(d * -0.01f);
  s += __expf(d * -0.1f);
  s += __expf(d * -1.0f);
  s += __expf(d * -10.0f);
  s += __expf(d * -100.0f);
  s += __expf(d * -1000.0f);
  red[tid] = (double)s;
  __syncthreads();
  #pragma unroll
  for (int st = 128; st > 0; st >>= 1) {
    if (tid < st) red[tid] += red[tid + st];
    __syncthreads();
  }
  if (tid == 0) atomicAdd(acc_out, red[0]);
}

// norms-only kernel for the fallback path (fallback doesn't use frag arrays).
__global__ __launch_bounds__(256) void norms_kernel(const float* __restrict__ x,
                                                    const float* __restrict__ y,
                                                    float* __restrict__ nx,
                                                    float* __restrict__ ny) {
  int tid = threadIdx.x;
  int g = tid & 3;
  int row = ((int)blockIdx.x & 127) * 64 + (tid >> 2);
  int arr = (int)blockIdx.x >> 7;
  const float* src = arr ? y : x;
  const float4* p = (const float4*)(src + (size_t)row * D) + g;
  float s = 0.f;
  #pragma unroll
  for (int i = 0; i < 8; i++) {
    float4 v = p[i * 4];
    s += v.x * v.x + v.y * v.y + v.z * v.z + v.w * v.w;
  }
  s += __shfl_xor(s, 1);
  s += __shfl_xor(s, 2);
  if (g == 0) (arr ? ny : nx)[row] = s;
}

__global__ void finalize_kernel(const double* __restrict__ acc,
                                float* __restrict__ out) {
  out[0] = (float)(acc[0] * (1.0 / ((double)N_PTS * (double)N_PTS)));
}

extern "C" void kernel_launch(void* const* d_in, const int* in_sizes, int n_in,
                              void* d_out, int out_size, void* d_ws, size_t ws_size,
                              hipStream_t stream) {
  const float* x = (const float*)d_in[0];
  const float* y = (const float*)d_in[1];
  float* out = (float*)d_out;

  char* ws = (char*)d_ws;
  double* acc = (double*)ws;                       // 8 B
  float* nx = (float*)(ws + 4096);                 // 8192 f
  float* ny = (float*)(ws + 36864);                // 8192 f
  const size_t FRAG_OFF = 69632;
  const size_t FRAG_SZ = 4194304;                  // 4 MB each
  const size_t NEED = FRAG_OFF + 2 * FRAG_SZ;      // proven fit (rounds 5..10)

  hipMemsetAsync(acc, 0, sizeof(double), stream);
  if (ws_size >= NEED) {
    unsigned short* xf = (unsigned short*)(ws + FRAG_OFF);
    unsigned short* yf = (unsigned short*)(ws + FRAG_OFF + FRAG_SZ);
    hipLaunchKernelGGL(convert_kernel, dim3(256), dim3(256), 0, stream,
                       x, y, xf, yf, nx, ny);
    hipLaunchKernelGGL(mmd_tile128_kernel, dim3(NBLK + NDIAG), dim3(256), 0, stream,
                       xf, yf, x, y, nx, ny, acc);
  } else {
    hipLaunchKernelGGL(norms_kernel, dim3(256), dim3(256), 0, stream, x, y, nx, ny);
    hipLaunchKernelGGL(mmd_fallback_kernel, dim3(NBLK), dim3(256), 0, stream, x, y, nx, ny, acc);
    hipLaunchKernelGGL(diag_kernel, dim3(64), dim3(256), 0, stream, x, y, nx, ny, acc);
  }
  hipLaunchKernelGGL(finalize_kernel, dim3(1), dim3(1), 0, stream, acc, out);
}